// Round 1
// baseline (195.482 us; speedup 1.0000x reference)
//
#include <hip/hip_runtime.h>

typedef unsigned short u16;
typedef unsigned int   u32;
typedef __bf16 bf16x8 __attribute__((ext_vector_type(8)));
typedef float  f32x4  __attribute__((ext_vector_type(4)));

#define SCALE 0.12751743f  // log2(e)/sqrt(128)

__device__ __forceinline__ u16 f2bf(float f) {
    u32 u = __builtin_bit_cast(u32, f);
    u32 r = (u + 0x7FFFu + ((u >> 16) & 1u)) >> 16;
    return (u16)r;
}
__device__ __forceinline__ u32 pk2(float a, float b) {
    return (u32)f2bf(a) | ((u32)f2bf(b) << 16);
}

// ---------------------------------------------------------------------------
// Phase 1: QKV projection.
// grid = B * (H/4) = 1024 blocks, 256 threads. Each block: (b, 4 h-rows, 64 w).
// Writes Qb, Kb as bf16 [pair][h][32]; V transposed: VT bf16 [pair][d][1024].
// ---------------------------------------------------------------------------
__global__ __launch_bounds__(256) void qkv_proj(
    const float* __restrict__ x,
    const float* __restrict__ wq, const float* __restrict__ bq,
    const float* __restrict__ wk, const float* __restrict__ bk,
    const float* __restrict__ wv, const float* __restrict__ bv,
    u16* __restrict__ Qb, u16* __restrict__ Kb, u16* __restrict__ VT)
{
    __shared__ float sW[3][32][32];
    __shared__ float sB[3][32];
    __shared__ u16   sVT[32][64][4];   // [c][w][hh]
    const int tid = threadIdx.x;
    const int b  = blockIdx.x >> 8;
    const int h0 = (blockIdx.x & 255) * 4;

    {
        const float* Ws[3] = {wq, wk, wv};
        for (int i = tid; i < 3072; i += 256)
            ((float*)sW)[i] = Ws[i >> 10][i & 1023];
        if (tid < 96) {
            const float* Bs[3] = {bq, bk, bv};
            ((float*)sB)[tid] = Bs[tid >> 5][tid & 31];
        }
    }
    __syncthreads();

    const int hh = tid >> 6, w = tid & 63;
    const int h = h0 + hh;

    float xv[32];
#pragma unroll
    for (int c = 0; c < 32; c++)
        xv[c] = x[(((size_t)b * 32 + c) * 1024 + h) * 64 + w];

    float qv[32], kv[32], vv[32];
#pragma unroll
    for (int co = 0; co < 32; co++) {
        float aq = sB[0][co], ak = sB[1][co], av = sB[2][co];
#pragma unroll
        for (int c = 0; c < 32; c++) {
            float xc = xv[c];
            aq += xc * sW[0][co][c];
            ak += xc * sW[1][co][c];
            av += xc * sW[2][co][c];
        }
        qv[co] = aq; kv[co] = ak; vv[co] = av;
    }

    const size_t pair = (size_t)b * 64 + w;
    const size_t base = (pair * 1024 + h) * 32;
    uint4* dq = (uint4*)(Qb + base);
    uint4* dk = (uint4*)(Kb + base);
#pragma unroll
    for (int t4 = 0; t4 < 4; t4++) {
        uint4 uq, uk;
        uq.x = pk2(qv[t4*8+0], qv[t4*8+1]); uq.y = pk2(qv[t4*8+2], qv[t4*8+3]);
        uq.z = pk2(qv[t4*8+4], qv[t4*8+5]); uq.w = pk2(qv[t4*8+6], qv[t4*8+7]);
        uk.x = pk2(kv[t4*8+0], kv[t4*8+1]); uk.y = pk2(kv[t4*8+2], kv[t4*8+3]);
        uk.z = pk2(kv[t4*8+4], kv[t4*8+5]); uk.w = pk2(kv[t4*8+6], kv[t4*8+7]);
        dq[t4] = uq;
        dk[t4] = uk;
    }

#pragma unroll
    for (int c = 0; c < 32; c++) sVT[c][w][hh] = f2bf(vv[c]);
    __syncthreads();

    for (int m = tid; m < 2048; m += 256) {
        int cc = m >> 6, ww = m & 63;
        uint2 val = *(const uint2*)&sVT[cc][ww][0];
        *(uint2*)(VT + (((size_t)b * 64 + ww) * 32 + cc) * 1024 + h0) = val;
    }
}

// ---------------------------------------------------------------------------
// Phase 2: attention. One block per (b,w) pair; 512 threads = 8 waves.
// K in LDS [kv][32] bf16 (16B-chunk swizzle: ch ^ ((kv>>1)&3)),
// VT in LDS [d][1024] bf16 (16B-chunk swizzle: ch ^ (d&7)).
// Swapped MFMA: S^T = mfma(K, Q). No max-subtraction (scores are small).
// O^T = mfma(V^T, P^T) accumulated over kv chunks of 32. Output [pair][d][h].
// ---------------------------------------------------------------------------
__global__ __launch_bounds__(512, 2) void attn(
    const u16* __restrict__ Qb, const u16* __restrict__ Kb,
    const u16* __restrict__ VT, float* __restrict__ Ow)
{
    __shared__ char sK[65536];
    __shared__ char sV[65536];
    __shared__ char sP[8][1280];   // per-wave P^T bounce: [16 q][40 bf16] (80B rows)

    const int tid = threadIdx.x;
    const int p = blockIdx.x;

    {
        const uint4* gK = (const uint4*)(Kb + (size_t)p * 32768);
        const uint4* gV = (const uint4*)(VT + (size_t)p * 32768);
        for (int m = tid; m < 4096; m += 512) {
            uint4 val = gK[m];
            int kv = m >> 2, ch = m & 3;
            *(uint4*)(sK + kv * 64 + ((ch ^ ((kv >> 1) & 3)) << 4)) = val;
        }
        for (int m = tid; m < 4096; m += 512) {
            uint4 val = gV[m];
            int d = m >> 7, ch = m & 127;
            *(uint4*)(sV + d * 2048 + ((ch ^ (d & 7)) << 4)) = val;
        }
    }
    __syncthreads();

    const int wid = tid >> 6, lane = tid & 63;
    const int g = lane >> 4, c = lane & 15;
    char* pb = sP[wid];

    // Q fragments (B-operand): lane reads Q[q0 + lane%16][8*(lane/16) .. +7]
    bf16x8 qf[8];
    {
        const u16* qbase = Qb + (size_t)p * 32768;
#pragma unroll
        for (int nq = 0; nq < 8; nq++) {
            int row = wid * 128 + nq * 16 + c;
            qf[nq] = __builtin_bit_cast(bf16x8, *(const uint4*)(qbase + row * 32 + g * 8));
        }
    }

    f32x4 o[8][2];
    float lsum[8];
    const f32x4 zz = {0.f, 0.f, 0.f, 0.f};
#pragma unroll
    for (int nq = 0; nq < 8; nq++) { o[nq][0] = zz; o[nq][1] = zz; lsum[nq] = 0.f; }

    for (int j = 0; j < 32; j++) {
        const int kv0 = j * 32;
        const int ra = kv0 + c;
        const int rb = ra + 16;
        bf16x8 k0 = __builtin_bit_cast(bf16x8,
            *(const uint4*)(sK + ra * 64 + ((g ^ ((ra >> 1) & 3)) << 4)));
        bf16x8 k1 = __builtin_bit_cast(bf16x8,
            *(const uint4*)(sK + rb * 64 + ((g ^ ((rb >> 1) & 3)) << 4)));
        const int chv = (kv0 >> 3) + g;
        bf16x8 v0 = __builtin_bit_cast(bf16x8,
            *(const uint4*)(sV + c * 2048 + ((chv ^ (c & 7)) << 4)));
        bf16x8 v1 = __builtin_bit_cast(bf16x8,
            *(const uint4*)(sV + (c + 16) * 2048 + ((chv ^ (c & 7)) << 4)));

#pragma unroll
        for (int nq = 0; nq < 8; nq++) {
            f32x4 s0 = __builtin_amdgcn_mfma_f32_16x16x32_bf16(k0, qf[nq], zz, 0, 0, 0);
            f32x4 s1 = __builtin_amdgcn_mfma_f32_16x16x32_bf16(k1, qf[nq], zz, 0, 0, 0);
            float p0[4], p1[4];
#pragma unroll
            for (int r = 0; r < 4; r++) {
                p0[r] = __builtin_amdgcn_exp2f(s0[r] * SCALE);
                p1[r] = __builtin_amdgcn_exp2f(s1[r] * SCALE);
            }
            lsum[nq] += (p0[0] + p0[1] + p0[2] + p0[3]) + (p1[0] + p1[1] + p1[2] + p1[3]);
            uint2 wa, wb;
            wa.x = pk2(p0[0], p0[1]); wa.y = pk2(p0[2], p0[3]);
            wb.x = pk2(p1[0], p1[1]); wb.y = pk2(p1[2], p1[3]);
            // P^T bounce through per-wave LDS (cross-lane within wave; DS is
            // in-order per wave — compiler-level fences stop reordering).
            asm volatile("" ::: "memory");
            *(uint2*)(pb + c * 80 + g * 8)      = wa;   // t=0 rows
            *(uint2*)(pb + c * 80 + 32 + g * 8) = wb;   // t=1 rows
            asm volatile("" ::: "memory");
            bf16x8 pf = __builtin_bit_cast(bf16x8, *(const uint4*)(pb + c * 80 + g * 16));
            o[nq][0] = __builtin_amdgcn_mfma_f32_16x16x32_bf16(v0, pf, o[nq][0], 0, 0, 0);
            o[nq][1] = __builtin_amdgcn_mfma_f32_16x16x32_bf16(v1, pf, o[nq][1], 0, 0, 0);
        }
    }

#pragma unroll
    for (int nq = 0; nq < 8; nq++) {
        float s = lsum[nq];
        s += __shfl_xor(s, 16, 64);
        s += __shfl_xor(s, 32, 64);
        const float inv = 1.0f / s;
        const int hq = wid * 128 + nq * 16 + c;
        float* dst = Ow + (size_t)p * 32768 + hq;
#pragma unroll
        for (int t = 0; t < 2; t++)
#pragma unroll
            for (int r = 0; r < 4; r++) {
                int d = t * 16 + g * 4 + r;
                dst[(size_t)d * 1024] = o[nq][t][r] * inv;
            }
    }
}

// ---------------------------------------------------------------------------
// Phase 3: transpose [pair][d][h] f32 -> out [b][d][h][w], fused *sum(w_lin)+b_lin.
// grid = 4*32*16 = 2048 blocks (b, d, h-tile of 64), 256 threads.
// ---------------------------------------------------------------------------
__global__ __launch_bounds__(256) void finalize_tr(
    const float* __restrict__ Ow, const float* __restrict__ w_lin,
    const float* __restrict__ b_lin, float* __restrict__ out)
{
    __shared__ float tile[64][65];
    const int tid = threadIdx.x;
    const int bi = blockIdx.x;
    const int b = bi >> 9, d = (bi >> 4) & 31, ht = bi & 15;
    const int h0 = ht * 64;

    float slin = 0.f;
#pragma unroll
    for (int i = 0; i < 8; i++) slin += w_lin[i];
    const float bl = b_lin[0];

    const int w = tid >> 2, part = tid & 3;
    const float4* src = (const float4*)(Ow + (((size_t)b * 64 + w) * 32 + d) * 1024 + h0 + part * 16);
#pragma unroll
    for (int i = 0; i < 4; i++) {
        float4 v = src[i];
        int hh = part * 16 + i * 4;
        tile[w][hh + 0] = v.x; tile[w][hh + 1] = v.y;
        tile[w][hh + 2] = v.z; tile[w][hh + 3] = v.w;
    }
    __syncthreads();

    const int ww = tid & 63, hb = tid >> 6;
    const size_t obase = ((size_t)b * 32 + d) * 1024 + h0;
#pragma unroll
    for (int k = 0; k < 16; k++) {
        int hh = k * 4 + hb;
        out[(obase + hh) * 64 + ww] = tile[ww][hh] * slin + bl;
    }
}

// ---------------------------------------------------------------------------
extern "C" void kernel_launch(void* const* d_in, const int* in_sizes, int n_in,
                              void* d_out, int out_size, void* d_ws, size_t ws_size,
                              hipStream_t stream)
{
    const float* x  = (const float*)d_in[0];
    const float* wq = (const float*)d_in[1];
    const float* bq = (const float*)d_in[2];
    const float* wk = (const float*)d_in[3];
    const float* bk = (const float*)d_in[4];
    const float* wv = (const float*)d_in[5];
    const float* bv = (const float*)d_in[6];
    const float* wl = (const float*)d_in[7];
    const float* bl = (const float*)d_in[8];
    float* out = (float*)d_out;

    char* ws = (char*)d_ws;
    u16*   Qb = (u16*)(ws);                    // 16 MB bf16 [256][1024][32]
    u16*   Kb = (u16*)(ws + (16u << 20));      // 16 MB bf16 [256][1024][32]
    u16*   VT = (u16*)(ws + (32u << 20));      // 16 MB bf16 [256][32][1024]
    float* Ow = (float*)(ws + (48u << 20));    // 32 MB f32  [256][32][1024]

    qkv_proj<<<1024, 256, 0, stream>>>(x, wq, bq, wk, bk, wv, bv, Qb, Kb, VT);
    attn<<<256, 512, 0, stream>>>(Qb, Kb, VT, Ow);
    finalize_tr<<<2048, 256, 0, stream>>>(Ow, wl, bl, out);
}

// Round 2
// 101.767 us; speedup vs baseline: 1.9209x; 1.9209x over previous
//
#include <hip/hip_runtime.h>

typedef unsigned short u16;
typedef unsigned int   u32;
typedef __bf16 bf16x8 __attribute__((ext_vector_type(8)));
typedef float  f32x4  __attribute__((ext_vector_type(4)));

#define KSCALE 0.12751743f  // log2(e)/sqrt(1024/8)

__device__ __forceinline__ u32 cvtpk(float lo, float hi) {
    u32 r;
    asm("v_cvt_pk_bf16_f32 %0, %1, %2" : "=v"(r) : "v"(lo), "v"(hi));
    return r;
}

// ---------------------------------------------------------------------------
// Phase 1: QKV projection. grid = B*(H/4) = 1024 blocks, 256 threads.
// Thread = (hh = tid>>6, w = tid&63); block covers (b, 4 h-rows, 64 w).
// Weights in LDS, read as b128 (4x fewer LDS instrs than scalar).
// K is pre-scaled by log2(e)/sqrt(128) (f32-exact, so attn uses exp2 directly).
// Outputs Q,K,V all bf16 [pair][h][32] pos-major, bounced through a swizzled
// LDS tile so global stores are 256B-contiguous per 16 lanes.
// ---------------------------------------------------------------------------
__global__ __launch_bounds__(256) void qkv_proj(
    const float* __restrict__ x,
    const float* __restrict__ wq, const float* __restrict__ bq,
    const float* __restrict__ wk, const float* __restrict__ bk,
    const float* __restrict__ wv, const float* __restrict__ bv,
    u16* __restrict__ Qb, u16* __restrict__ Kb, u16* __restrict__ Vb)
{
    __shared__ float sW[3][32][32];
    __shared__ float sB[3][32];
    __shared__ u16   sO[8192];    // bounce: logical [w][hh][32c], 16B-chunk swizzled
    const int tid = threadIdx.x;
    const int b  = blockIdx.x >> 8;
    const int h0 = (blockIdx.x & 255) * 4;

    {
        const float* Ws[3] = {wq, wk, wv};
        for (int i = tid; i < 3072; i += 256) {
            float v = Ws[i >> 10][i & 1023];
            if ((i >> 10) == 1) v *= KSCALE;
            ((float*)sW)[i] = v;
        }
        if (tid < 96) {
            const float* Bs[3] = {bq, bk, bv};
            float v = Bs[tid >> 5][tid & 31];
            if ((tid >> 5) == 1) v *= KSCALE;
            ((float*)sB)[tid] = v;
        }
    }
    __syncthreads();

    const int hh = tid >> 6, w = tid & 63;
    const int h = h0 + hh;

    float xv[32];
#pragma unroll
    for (int c = 0; c < 32; c++)
        xv[c] = x[(((size_t)b * 32 + c) * 1024 + h) * 64 + w];

    u16* outs[3] = {Qb, Kb, Vb};
    const size_t gb = (size_t)b * 2097152 + (size_t)h0 * 32;
    uint4* so4 = (uint4*)sO;

#pragma unroll
    for (int m = 0; m < 3; m++) {
        float acc[32];
#pragma unroll
        for (int co = 0; co < 32; co++) {
            const float4* wr = (const float4*)&sW[m][co][0];
            float a = sB[m][co];
#pragma unroll
            for (int c4 = 0; c4 < 8; c4++) {
                float4 w4 = wr[c4];
                a += xv[c4*4+0]*w4.x + xv[c4*4+1]*w4.y + xv[c4*4+2]*w4.z + xv[c4*4+3]*w4.w;
            }
            acc[co] = a;
        }
        if (m) __syncthreads();   // previous matrix's readback done
#pragma unroll
        for (int s = 0; s < 4; s++) {
            uint4 u;
            u.x = cvtpk(acc[s*8+0], acc[s*8+1]);
            u.y = cvtpk(acc[s*8+2], acc[s*8+3]);
            u.z = cvtpk(acc[s*8+4], acc[s*8+5]);
            u.w = cvtpk(acc[s*8+6], acc[s*8+7]);
            int L = w*16 + hh*4 + s;          // logical 16B-chunk index
            so4[L ^ (w & 7)] = u;             // bank-quad spread
        }
        __syncthreads();
        u16* g = outs[m] + gb;
#pragma unroll
        for (int j = 0; j < 4; j++) {
            int L = tid + j*256;
            uint4 val = so4[L ^ ((L >> 4) & 7)];
            int w_ = L >> 4, hh_ = (L >> 2) & 3, sub = L & 3;
            *(uint4*)(g + (size_t)w_*32768 + hh_*32 + sub*8) = val;
        }
        if (m < 2) __syncthreads();
    }
}

// ---------------------------------------------------------------------------
// Phase 2: attention. One block per (b,w) pair; 512 threads = 8 waves.
// K in LDS with PERMUTED row slots: within each 32-kv chunk, slot
//   s = ((q&4)<<2)|((q&24)>>1)|(q&3)   (tile X rows: kv=8(r>>2)+(r&3); Y: +4)
// so the QK^T C-fragment rows a lane holds (kv=8g+r and 8g+4+r) are exactly
// the PV B-fragment k-indices (k=8g+j) -> zero cross-lane P redistribution.
// V transposed into LDS [d][kv] during staging via b16 scatter, XOR-swizzled
// (^(d&7)^((d>>3)&3)) so both scatter-writes and fragment-reads are <=2-way.
// ---------------------------------------------------------------------------
__global__ __launch_bounds__(512, 2) void attn(
    const u16* __restrict__ Qb, const u16* __restrict__ Kb,
    const u16* __restrict__ Vb, float* __restrict__ Ow)
{
    __shared__ char sK[65536];
    __shared__ char sV[65536];
    const int tid = threadIdx.x;
    const int p = blockIdx.x;

    {
        const uint4* gK = (const uint4*)(Kb + (size_t)p * 32768);
        for (int m = tid; m < 4096; m += 512) {
            uint4 val = gK[m];
            int kv = m >> 2, ch = m & 3;
            int q = kv & 31;
            int slot = (kv & ~31) | ((q & 4) << 2) | ((q & 24) >> 1) | (q & 3);
            *(uint4*)(sK + slot * 64 + ((ch ^ ((slot >> 1) & 3)) << 4)) = val;
        }
        const uint4* gV = (const uint4*)(Vb + (size_t)p * 32768);
        for (int m = tid; m < 4096; m += 512) {
            uint4 val = gV[m];
            int kv = m >> 2, c0 = (m & 3) * 8;
            const u16* pv = (const u16*)&val;
#pragma unroll
            for (int k = 0; k < 8; k++) {
                int d = c0 + k;
                int chv = (kv >> 3) ^ (d & 7) ^ ((d >> 3) & 3);
                *(u16*)(sV + d * 2048 + (chv << 4) + (kv & 7) * 2) = pv[k];
            }
        }
    }
    __syncthreads();

    const int wid = tid >> 6, lane = tid & 63;
    const int g = lane >> 4, c = lane & 15;

    bf16x8 qf[8];
    {
        const u16* qbase = Qb + (size_t)p * 32768;
#pragma unroll
        for (int nq = 0; nq < 8; nq++) {
            int row = wid * 128 + nq * 16 + c;
            qf[nq] = __builtin_bit_cast(bf16x8, *(const uint4*)(qbase + row * 32 + g * 8));
        }
    }

    f32x4 o[8][2];
    float lsum[8];
    const f32x4 zz = {0.f, 0.f, 0.f, 0.f};
#pragma unroll
    for (int nq = 0; nq < 8; nq++) { o[nq][0] = zz; o[nq][1] = zz; lsum[nq] = 0.f; }

    for (int j = 0; j < 32; j++) {
        const int kv0 = j * 32;
        const int ra = kv0 + c;          // tile X slot row
        const int rb = ra + 16;          // tile Y slot row
        bf16x8 k0 = __builtin_bit_cast(bf16x8,
            *(const uint4*)(sK + ra * 64 + ((g ^ ((ra >> 1) & 3)) << 4)));
        bf16x8 k1 = __builtin_bit_cast(bf16x8,
            *(const uint4*)(sK + rb * 64 + ((g ^ ((rb >> 1) & 3)) << 4)));
        const int cb = (kv0 >> 3) + g;
        bf16x8 v0 = __builtin_bit_cast(bf16x8,
            *(const uint4*)(sV + c * 2048 + ((cb ^ (c & 7) ^ ((c >> 3) & 3)) << 4)));
        bf16x8 v1 = __builtin_bit_cast(bf16x8,
            *(const uint4*)(sV + (c + 16) * 2048 + ((cb ^ (c & 7) ^ (((c + 16) >> 3) & 3)) << 4)));

#pragma unroll
        for (int nq = 0; nq < 8; nq++) {
            f32x4 s0 = __builtin_amdgcn_mfma_f32_16x16x32_bf16(k0, qf[nq], zz, 0, 0, 0);
            f32x4 s1 = __builtin_amdgcn_mfma_f32_16x16x32_bf16(k1, qf[nq], zz, 0, 0, 0);
            float p0[4], p1[4];
#pragma unroll
            for (int r = 0; r < 4; r++) {
                p0[r] = __builtin_amdgcn_exp2f(s0[r]);   // scale folded into K
                p1[r] = __builtin_amdgcn_exp2f(s1[r]);
            }
            lsum[nq] += (p0[0] + p0[1] + p0[2] + p0[3]) + (p1[0] + p1[1] + p1[2] + p1[3]);
            uint4 pw;
            pw.x = cvtpk(p0[0], p0[1]);   // kv 8g+0,1
            pw.y = cvtpk(p0[2], p0[3]);   // kv 8g+2,3
            pw.z = cvtpk(p1[0], p1[1]);   // kv 8g+4,5
            pw.w = cvtpk(p1[2], p1[3]);   // kv 8g+6,7
            bf16x8 pf = __builtin_bit_cast(bf16x8, pw);
            o[nq][0] = __builtin_amdgcn_mfma_f32_16x16x32_bf16(v0, pf, o[nq][0], 0, 0, 0);
            o[nq][1] = __builtin_amdgcn_mfma_f32_16x16x32_bf16(v1, pf, o[nq][1], 0, 0, 0);
        }
    }

#pragma unroll
    for (int nq = 0; nq < 8; nq++) {
        float s = lsum[nq];
        s += __shfl_xor(s, 16, 64);
        s += __shfl_xor(s, 32, 64);
        const float inv = 1.0f / s;
        const int hq = wid * 128 + nq * 16 + c;
        float* dst = Ow + (size_t)p * 32768 + hq;
#pragma unroll
        for (int t = 0; t < 2; t++)
#pragma unroll
            for (int r = 0; r < 4; r++) {
                int d = t * 16 + g * 4 + r;
                dst[(size_t)d * 1024] = o[nq][t][r] * inv;
            }
    }
}

// ---------------------------------------------------------------------------
// Phase 3: transpose [pair][d][h] f32 -> out [b][d][h][w], fused *sum(w_lin)+b_lin.
// grid = 4*32*16 = 2048 blocks (b, d, h-tile of 64), 256 threads.
// ---------------------------------------------------------------------------
__global__ __launch_bounds__(256) void finalize_tr(
    const float* __restrict__ Ow, const float* __restrict__ w_lin,
    const float* __restrict__ b_lin, float* __restrict__ out)
{
    __shared__ float tile[64][65];
    const int tid = threadIdx.x;
    const int bi = blockIdx.x;
    const int b = bi >> 9, d = (bi >> 4) & 31, ht = bi & 15;
    const int h0 = ht * 64;

    float slin = 0.f;
#pragma unroll
    for (int i = 0; i < 8; i++) slin += w_lin[i];
    const float bl = b_lin[0];

    const int w = tid >> 2, part = tid & 3;
    const float4* src = (const float4*)(Ow + (((size_t)b * 64 + w) * 32 + d) * 1024 + h0 + part * 16);
#pragma unroll
    for (int i = 0; i < 4; i++) {
        float4 v = src[i];
        int hh = part * 16 + i * 4;
        tile[w][hh + 0] = v.x; tile[w][hh + 1] = v.y;
        tile[w][hh + 2] = v.z; tile[w][hh + 3] = v.w;
    }
    __syncthreads();

    const int ww = tid & 63, hb = tid >> 6;
    const size_t obase = ((size_t)b * 32 + d) * 1024 + h0;
#pragma unroll
    for (int k = 0; k < 16; k++) {
        int hh = k * 4 + hb;
        out[(obase + hh) * 64 + ww] = tile[ww][hh] * slin + bl;
    }
}

// ---------------------------------------------------------------------------
extern "C" void kernel_launch(void* const* d_in, const int* in_sizes, int n_in,
                              void* d_out, int out_size, void* d_ws, size_t ws_size,
                              hipStream_t stream)
{
    const float* x  = (const float*)d_in[0];
    const float* wq = (const float*)d_in[1];
    const float* bq = (const float*)d_in[2];
    const float* wk = (const float*)d_in[3];
    const float* bk = (const float*)d_in[4];
    const float* wv = (const float*)d_in[5];
    const float* bv = (const float*)d_in[6];
    const float* wl = (const float*)d_in[7];
    const float* bl = (const float*)d_in[8];
    float* out = (float*)d_out;

    char* ws = (char*)d_ws;
    u16*   Qb = (u16*)(ws);                    // 16 MiB bf16 [256][1024][32]
    u16*   Kb = (u16*)(ws + (16u << 20));      // 16 MiB bf16 [256][1024][32] (pre-scaled)
    u16*   Vb = (u16*)(ws + (32u << 20));      // 16 MiB bf16 [256][1024][32] pos-major
    float* Ow = (float*)(ws + (48u << 20));    // 32 MiB f32  [256][32][1024]

    qkv_proj<<<1024, 256, 0, stream>>>(x, wq, bq, wk, bk, wv, bv, Qb, Kb, Vb);
    attn<<<256, 512, 0, stream>>>(Qb, Kb, Vb, Ow);
    finalize_tr<<<2048, 256, 0, stream>>>(Ow, wl, bl, out);
}